// Round 1
// baseline (409.198 us; speedup 1.0000x reference)
//
#include <hip/hip_runtime.h>
#include <hip/hip_bf16.h>

// Problem constants (from reference): B=512, T=2048, S=16, H=128, A=4
#define HDIM 128
#define SDIM 16
#define ADIM 4
#define NREC 40          // packed per-j weight record, floats (16B-aligned stride: 160B)
#define NTOK (512 * 2048)

__device__ __forceinline__ float fast_tanh(float x) {
    // tanh(x) = 1 - 2/(1+e^{2x}); safe at +/-inf: e->inf -> 1 ; e->0 -> -1
    float e = __expf(2.0f * x);
    return 1.0f - 2.0f * __builtin_amdgcn_rcpf(e + 1.0f);
}

__global__ __launch_bounds__(256) void cbf_qp_kernel(
    const float* __restrict__ state,
    const float* __restrict__ Wc1, const float* __restrict__ bc1,
    const float* __restrict__ Wc2, const float* __restrict__ bc2,
    const float* __restrict__ Wh1, const float* __restrict__ bh1,
    const float* __restrict__ wh2, const float* __restrict__ bh2,
    const float* __restrict__ Wf,  const float* __restrict__ bf,
    const float* __restrict__ Wg,  const float* __restrict__ bg,
    float* __restrict__ out)
{
    // ---- LDS weight cache ------------------------------------------------
    __shared__ float rec[HDIM * NREC];   // per-j: Wc1 col(16) | Wh1 col(16) | Wc2 row(4) | bc1,bh1,wh2,pad
    __shared__ float wg_s[SDIM * 64];    // Wg row-major [16][64]
    __shared__ float wf_s[SDIM * SDIM];  // Wf row-major [16][16]
    __shared__ float bg_s[64];
    __shared__ float bf_s[SDIM];
    __shared__ float bc2_s[ADIM];
    __shared__ float bh2_s;

    const int tid = threadIdx.x;
    if (tid < HDIM) {
        const int j = tid;
        #pragma unroll
        for (int k = 0; k < SDIM; ++k) {
            rec[j * NREC + k]        = Wc1[k * HDIM + j];   // column j of Wc1
            rec[j * NREC + 16 + k]   = Wh1[k * HDIM + j];   // column j of Wh1
        }
        #pragma unroll
        for (int a = 0; a < ADIM; ++a) rec[j * NREC + 32 + a] = Wc2[j * ADIM + a];
        rec[j * NREC + 36] = bc1[j];
        rec[j * NREC + 37] = bh1[j];
        rec[j * NREC + 38] = wh2[j];
        rec[j * NREC + 39] = 0.0f;
    } else {
        const int t = tid - HDIM;   // 0..127
        for (int m = t; m < SDIM * 64; m += HDIM) wg_s[m] = Wg[m];
        for (int m = t; m < SDIM * SDIM; m += HDIM) wf_s[m] = Wf[m];
        if (t < 64)      bg_s[t]       = bg[t];
        else if (t < 80) bf_s[t - 64]  = bf[t - 64];
        else if (t < 84) bc2_s[t - 80] = bc2[t - 80];
        else if (t == 84) bh2_s        = bh2[0];
    }
    __syncthreads();

    // ---- per-token compute ----------------------------------------------
    const int n = blockIdx.x * 256 + tid;   // 4096 blocks * 256 = NTOK exactly

    float sv[16];
    {
        const float4* sp = reinterpret_cast<const float4*>(state + (size_t)n * SDIM);
        float4 a = sp[0], b = sp[1], c = sp[2], d = sp[3];
        sv[0]=a.x;  sv[1]=a.y;  sv[2]=a.z;  sv[3]=a.w;
        sv[4]=b.x;  sv[5]=b.y;  sv[6]=b.z;  sv[7]=b.w;
        sv[8]=c.x;  sv[9]=c.y;  sv[10]=c.z; sv[11]=c.w;
        sv[12]=d.x; sv[13]=d.y; sv[14]=d.z; sv[15]=d.w;
    }

    float ua0 = 0.f, ua1 = 0.f, ua2 = 0.f, ua3 = 0.f;   // t1 @ Wc2 accumulator
    float h = 0.f;                                      // t2 . wh2
    float dh[16];
    #pragma unroll
    for (int k = 0; k < 16; ++k) dh[k] = 0.f;

    #pragma unroll 4
    for (int j = 0; j < HDIM; ++j) {
        const float4* r = reinterpret_cast<const float4*>(&rec[j * NREC]);
        float4 c0 = r[0], c1 = r[1], c2 = r[2], c3 = r[3];   // Wc1 col
        float4 m0 = r[4], m1 = r[5], m2 = r[6], m3 = r[7];   // Wh1 col
        float4 w2 = r[8];                                    // Wc2 row j
        float4 bb = r[9];                                    // bc1, bh1, wh2, pad

        float z1 = bb.x
            + sv[0]*c0.x  + sv[1]*c0.y  + sv[2]*c0.z  + sv[3]*c0.w
            + sv[4]*c1.x  + sv[5]*c1.y  + sv[6]*c1.z  + sv[7]*c1.w
            + sv[8]*c2.x  + sv[9]*c2.y  + sv[10]*c2.z + sv[11]*c2.w
            + sv[12]*c3.x + sv[13]*c3.y + sv[14]*c3.z + sv[15]*c3.w;
        float z2 = bb.y
            + sv[0]*m0.x  + sv[1]*m0.y  + sv[2]*m0.z  + sv[3]*m0.w
            + sv[4]*m1.x  + sv[5]*m1.y  + sv[6]*m1.z  + sv[7]*m1.w
            + sv[8]*m2.x  + sv[9]*m2.y  + sv[10]*m2.z + sv[11]*m2.w
            + sv[12]*m3.x + sv[13]*m3.y + sv[14]*m3.z + sv[15]*m3.w;

        float t1 = fast_tanh(z1);
        float t2 = fast_tanh(z2);

        ua0 += t1 * w2.x; ua1 += t1 * w2.y; ua2 += t1 * w2.z; ua3 += t1 * w2.w;
        h   += bb.z * t2;

        float dj = bb.z * (1.0f - t2 * t2);   // wh2[j] * sech^2(z2)
        dh[0]  += m0.x * dj; dh[1]  += m0.y * dj; dh[2]  += m0.z * dj; dh[3]  += m0.w * dj;
        dh[4]  += m1.x * dj; dh[5]  += m1.y * dj; dh[6]  += m1.z * dj; dh[7]  += m1.w * dj;
        dh[8]  += m2.x * dj; dh[9]  += m2.y * dj; dh[10] += m2.z * dj; dh[11] += m2.w * dj;
        dh[12] += m3.x * dj; dh[13] += m3.y * dj; dh[14] += m3.z * dj; dh[15] += m3.w * dj;
    }

    // ---- right = h + bh2 + dh . (s @ Wf + bf) ---------------------------
    float right = h + bh2_s;
    {
        const float4* wf4 = reinterpret_cast<const float4*>(wf_s);
        const float4* bf4 = reinterpret_cast<const float4*>(bf_s);
        #pragma unroll
        for (int i4 = 0; i4 < 4; ++i4) {
            float4 f = bf4[i4];
            #pragma unroll
            for (int k = 0; k < 16; ++k) {
                float4 w = wf4[k * 4 + i4];   // Wf[k][i4*4 .. i4*4+3]
                f.x += sv[k] * w.x; f.y += sv[k] * w.y;
                f.z += sv[k] * w.z; f.w += sv[k] * w.w;
            }
            right += dh[i4*4+0]*f.x + dh[i4*4+1]*f.y + dh[i4*4+2]*f.z + dh[i4*4+3]*f.w;
        }
    }

    // ---- left[a] = -sum_s dh[s] * g[s][a],  g = s @ Wg + bg -------------
    float l0 = 0.f, l1 = 0.f, l2v = 0.f, l3 = 0.f;
    {
        const float4* wg4 = reinterpret_cast<const float4*>(wg_s);
        const float4* bg4 = reinterpret_cast<const float4*>(bg_s);
        #pragma unroll
        for (int si = 0; si < 16; ++si) {
            float4 g = bg4[si];
            #pragma unroll
            for (int k = 0; k < 16; ++k) {
                float4 w = wg4[k * 16 + si];  // Wg[k][si*4 .. si*4+3]
                g.x += sv[k] * w.x; g.y += sv[k] * w.y;
                g.z += sv[k] * w.z; g.w += sv[k] * w.w;
            }
            float d = dh[si];
            l0 -= d * g.x; l1 -= d * g.y; l2v -= d * g.z; l3 -= d * g.w;
        }
    }

    // ---- closed-form QP --------------------------------------------------
    float u0 = 2.0f * (ua0 + bc2_s[0]);
    float u1 = 2.0f * (ua1 + bc2_s[1]);
    float u2 = 2.0f * (ua2 + bc2_s[2]);
    float u3 = 2.0f * (ua3 + bc2_s[3]);

    float viol = l0*u0 + l1*u1 + l2v*u2 + l3*u3 - right;
    float lsq  = l0*l0 + l1*l1 + l2v*l2v + l3*l3;
    float lam  = viol > 0.0f ? viol / (lsq + 1e-8f) : 0.0f;

    float4 u;
    u.x = u0 - lam * l0;
    u.y = u1 - lam * l1;
    u.z = u2 - lam * l2v;
    u.w = u3 - lam * l3;
    reinterpret_cast<float4*>(out)[n] = u;
}

extern "C" void kernel_launch(void* const* d_in, const int* in_sizes, int n_in,
                              void* d_out, int out_size, void* d_ws, size_t ws_size,
                              hipStream_t stream) {
    (void)in_sizes; (void)n_in; (void)d_ws; (void)ws_size; (void)out_size;
    const float* state = (const float*)d_in[0];
    const float* Wc1   = (const float*)d_in[1];
    const float* bc1   = (const float*)d_in[2];
    const float* Wc2   = (const float*)d_in[3];
    const float* bc2   = (const float*)d_in[4];
    const float* Wh1   = (const float*)d_in[5];
    const float* bh1   = (const float*)d_in[6];
    const float* wh2   = (const float*)d_in[7];
    const float* bh2   = (const float*)d_in[8];
    const float* Wf    = (const float*)d_in[9];
    const float* bf    = (const float*)d_in[10];
    const float* Wg    = (const float*)d_in[11];
    const float* bg    = (const float*)d_in[12];
    float* out = (float*)d_out;

    dim3 grid(NTOK / 256);
    dim3 block(256);
    hipLaunchKernelGGL(cbf_qp_kernel, grid, block, 0, stream,
                       state, Wc1, bc1, Wc2, bc2, Wh1, bh1, wh2, bh2,
                       Wf, bf, Wg, bg, out);
}